// Round 4
// baseline (200.162 us; speedup 1.0000x reference)
//
#include <hip/hip_runtime.h>
#include <math.h>

#define KK 15
#define K1 16
#define NN 4096
#define BSZ 128
#define NT 512
#define RPT 8          // rows per thread = NN/NT
#define NPAIR 4        // packed row pairs per thread
#define NW 8           // waves per block
#define EPSI 0.1f
#define SMALLC 1e-20f
#define NITER 200
#define W2STRIDE 65536
#define OUT_A_ELEMS (BSZ * NN * KK)
#define TS 20          // wbufT row stride in floats (2-way bank alias only, free)
#define CONV_REL 5e-7f

typedef __attribute__((ext_vector_type(2))) float f2;
typedef __attribute__((ext_vector_type(2))) unsigned u2v;
__device__ __forceinline__ f2 pk_fma(f2 a, f2 b, f2 c){
  return __builtin_elementwise_fma(a, b, c);
}

// ---------- sortable float <-> uint encoding for atomic min/max ----------
__device__ __forceinline__ unsigned enc_f32(float f){
  unsigned u = __float_as_uint(f);
  return (u & 0x80000000u) ? ~u : (u | 0x80000000u);
}
__device__ __forceinline__ float dec_f32(unsigned e){
  unsigned u = (e & 0x80000000u) ? (e ^ 0x80000000u) : ~e;
  return __uint_as_float(u);
}

// ws layout (uint32): [0]=max_enc(0) [1]=neg_flag(0) [2]=norm^2 f32(0)
//                     [3]=arrive(0) [4]=done(0) [5]=min_enc(0xFFFFFFFF)

// ---------- DPP cross-lane mov (VALU pipe, not DS) ----------
template<int CTRL>
__device__ __forceinline__ float dpp_movf(float x){
  return __uint_as_float((unsigned)__builtin_amdgcn_update_dpp(
      (int)0, (int)__float_as_uint(x), CTRL, 0xF, 0xF, true));
}

// xor16 / xor32 sums via permlane swaps (VALU pipe); shfl fallback if builtin missing
__device__ __forceinline__ float xsum16(float r){
#if __has_builtin(__builtin_amdgcn_permlane16_swap)
  u2v s = __builtin_amdgcn_permlane16_swap(__float_as_uint(r), __float_as_uint(r), false, false);
  return __uint_as_float(s.x) + __uint_as_float(s.y);
#else
  return r + __shfl_xor(r, 16);
#endif
}
__device__ __forceinline__ float xsum32(float r){
#if __has_builtin(__builtin_amdgcn_permlane32_swap)
  u2v s = __builtin_amdgcn_permlane32_swap(__float_as_uint(r), __float_as_uint(r), false, false);
  return __uint_as_float(s.x) + __uint_as_float(s.y);
#else
  return r + __shfl_xor(r, 32);
#endif
}

// ---------- 16-column lane-fold reduction (DPP-based) ----------
// Stage masks: 1 (quad_perm), 2 (quad_perm), 8 (row_ror:8), 4 (ds shfl), then
// xor16/xor32 permlane sums. Column bit assignment: b3<-l&1, b2<-l&2, b1<-l&8, b0<-l&4.
__device__ __forceinline__ int fold_col(int lane){
  int l = lane & 15;
  return ((l & 1) << 3) | ((l & 2) << 1) | ((l & 8) >> 2) | ((l & 4) >> 2);
}

__device__ __forceinline__ float wave_fold16(const float p[K1], int lane){
  float a[8];
  {
    const bool hi = (lane & 1) != 0;
    #pragma unroll
    for (int j = 0; j < 8; ++j){
      float send = hi ? p[j] : p[j + 8];
      float keep = hi ? p[j + 8] : p[j];
      a[j] = keep + dpp_movf<0xB1>(send);       // quad_perm [1,0,3,2] == xor1
    }
  }
  float bq[4];
  {
    const bool hi = (lane & 2) != 0;
    #pragma unroll
    for (int j = 0; j < 4; ++j){
      float send = hi ? a[j] : a[j + 4];
      float keep = hi ? a[j + 4] : a[j];
      bq[j] = keep + dpp_movf<0x4E>(send);      // quad_perm [2,3,0,1] == xor2
    }
  }
  float cq[2];
  {
    const bool hi = (lane & 8) != 0;
    float s0 = hi ? bq[0] : bq[2];
    float s1 = hi ? bq[1] : bq[3];
    float k0 = hi ? bq[2] : bq[0];
    float k1 = hi ? bq[3] : bq[1];
    cq[0] = k0 + dpp_movf<0x128>(s0);           // row_ror:8 == xor8 within 16
    cq[1] = k1 + dpp_movf<0x128>(s1);
  }
  float r;
  {
    const bool hi = (lane & 4) != 0;
    float send = hi ? cq[0] : cq[1];
    float keep = hi ? cq[1] : cq[0];
    r = keep + __shfl_xor(send, 4);             // the one remaining DS op
  }
  r = xsum16(r);
  r = xsum32(r);
  return r;
}

__device__ __forceinline__ void block_fold16(const float p[K1], float* wb, float* tb,
                                             int lane, int wv, int tid){
  float r = wave_fold16(p, lane);
  if (lane < 16) wb[wv * K1 + fold_col(lane)] = r;
  __syncthreads();
  if (tid < 16){
    float t = 0.0f;
    #pragma unroll
    for (int q = 0; q < NW; ++q) t += wb[q * K1 + tid];
    tb[tid] = t;
  }
  __syncthreads();
}

// One Sinkhorn half-step's math: row sums (Horner) -> t2, col partials, wave fold.
__device__ __forceinline__ float iter_math(const float vt[K1], const f2 x2[NPAIR],
                                           const f2 xp[NPAIR][K1], f2 t2[NPAIR],
                                           int lane){
  #pragma unroll
  for (int q = 0; q < NPAIR; ++q){
    f2 h; h.x = vt[KK]; h.y = vt[KK];
    #pragma unroll
    for (int c = KK - 1; c >= 0; --c){
      f2 vc; vc.x = vt[c]; vc.y = vt[c];
      h = pk_fma(h, x2[q], vc);
    }
    t2[q].x = __builtin_amdgcn_rcpf(h.x);
    t2[q].y = __builtin_amdgcn_rcpf(h.y);
  }
  float p[K1];
  #pragma unroll
  for (int c = 0; c < K1; ++c){
    f2 s = t2[0] * xp[0][c];
    #pragma unroll
    for (int q = 1; q < NPAIR; ++q) s = pk_fma(t2[q], xp[q][c], s);
    p[c] = s.x + s.y;
  }
  return wave_fold16(p, lane);
}

__global__ __launch_bounds__(NT, 2) void k_main(
    const float* __restrict__ scores, const float* __restrict__ taup,
    const float* __restrict__ w1, const float* __restrict__ w2,
    float* __restrict__ out, unsigned* __restrict__ ws){
  const int b = blockIdx.x;
  const int tid = threadIdx.x;
  const int lane = tid & 63;
  const int wv = tid >> 6;

  __shared__ float scratch[NN];
  __shared__ float tk[KK];
  __shared__ int tki[KK];
  __shared__ __align__(16) float cbuf[K1];
  __shared__ float wbuf[NW * K1];
  __shared__ __align__(16) float xbuf[K1];
  __shared__ __align__(16) float wbufT[2][K1 * TS];
  __shared__ float rv[NW];
  __shared__ int ri[NW];
  __shared__ float rmn[NW];
  __shared__ unsigned sng[NW];
  __shared__ float statb[4];

  // ---- load raw row ----
  float raw[RPT];
  #pragma unroll
  for (int j = 0; j < RPT; ++j) raw[j] = scores[(size_t)b * NN + tid + NT * j];

  // ---- fused global min/max/neg + device spin-barrier ----
  {
    float mx = -INFINITY, mn = INFINITY; unsigned neg = 0u;
    #pragma unroll
    for (int j = 0; j < RPT; ++j){
      float v = raw[j];
      mx = fmaxf(mx, v);
      if (v == -INFINITY) neg = 1u; else mn = fminf(mn, v);
    }
    #pragma unroll
    for (int off = 32; off; off >>= 1){
      mx = fmaxf(mx, __shfl_xor(mx, off));
      mn = fminf(mn, __shfl_xor(mn, off));
      neg |= (unsigned)__shfl_xor((int)neg, off);
    }
    if (lane == 0){ rv[wv] = mx; rmn[wv] = mn; sng[wv] = neg; }
    __syncthreads();
    if (tid == 0){
      for (int q = 1; q < NW; ++q){
        mx = fmaxf(mx, rv[q]); mn = fminf(mn, rmn[q]); neg |= sng[q];
      }
      atomicMax(&ws[0], enc_f32(mx));
      atomicMin(&ws[5], enc_f32(mn));
      if (neg) atomicOr(&ws[1], 1u);
      __threadfence();
      atomicAdd(&ws[3], 1u);
      while (__hip_atomic_load(&ws[3], __ATOMIC_ACQUIRE, __HIP_MEMORY_SCOPE_AGENT) < (unsigned)BSZ)
        __builtin_amdgcn_s_sleep(2);
      statb[0] = dec_f32(__hip_atomic_load(&ws[0], __ATOMIC_RELAXED, __HIP_MEMORY_SCOPE_AGENT));
      statb[1] = dec_f32(__hip_atomic_load(&ws[5], __ATOMIC_RELAXED, __HIP_MEMORY_SCOPE_AGENT));
      statb[2] = __hip_atomic_load(&ws[1], __ATOMIC_RELAXED, __HIP_MEMORY_SCOPE_AGENT) ? 1.0f : 0.0f;
    }
    __syncthreads();
  }

  const float smax = statb[0];
  const float smin_raw = statb[1];
  const bool has_neg = statb[2] != 0.0f;
  const float filled = smin_raw - (smax - smin_raw);
  const float smin_eff = has_neg ? filled : smin_raw;
  const float cmax = fmaxf(fmaxf(smin_eff * smin_eff, smax * smax),
                           fmaxf((smin_eff - 15.0f) * (smin_eff - 15.0f),
                                 (smax - 15.0f) * (smax - 15.0f)));
  const float cinv = 1.0f / cmax;
  const float tauv = taup[0];
  const float inv_n = 1.0f / (float)NN;   // 2^-12, exact

  // ---- fixed s values into scratch (also used for top-k) ----
  #pragma unroll
  for (int j = 0; j < RPT; ++j){
    float v = raw[j]; if (v == -INFINITY) v = filled;
    scratch[tid + NT * j] = v;
  }
  __syncthreads();

  // ---- top-15 by iterative argmax (record indices for restore) ----
  for (int t = 0; t < KK; ++t){
    float bv = -INFINITY; int bi = NN;
    #pragma unroll
    for (int j = 0; j < RPT; ++j){
      int i = tid + NT * j;
      float v = scratch[i];
      if (v > bv){ bv = v; bi = i; }
    }
    #pragma unroll
    for (int off = 32; off; off >>= 1){
      float ov = __shfl_xor(bv, off);
      int oi = __shfl_xor(bi, off);
      if (ov > bv || (ov == bv && oi < bi)){ bv = ov; bi = oi; }
    }
    if (lane == 0){ rv[wv] = bv; ri[wv] = bi; }
    __syncthreads();
    if (tid == 0){
      for (int q = 1; q < NW; ++q){
        if (rv[q] > bv || (rv[q] == bv && ri[q] < bi)){ bv = rv[q]; bi = ri[q]; }
      }
      tk[t] = bv;
      tki[t] = bi;
      scratch[bi] = -INFINITY;
    }
    __syncthreads();
  }
  // restore the 15 extracted values so scratch holds the full filled s row
  if (tid < KK) scratch[tki[tid]] = tk[tid];
  __syncthreads();

  // ---- Gamma0 column sums ----
  {
    float p[K1];
    float tkr[KK];
    #pragma unroll
    for (int c = 0; c < KK; ++c) tkr[c] = tk[c];
    #pragma unroll
    for (int c = 0; c < K1; ++c) p[c] = 0.0f;
    #pragma unroll
    for (int j = 0; j < RPT; ++j){
      float si = scratch[tid + NT * j];
      #pragma unroll
      for (int c = 0; c < KK; ++c){
        float z = fabsf(tkr[c] - si) / tauv;
        float raw1 = 1.0f / (1.0f + expf(z)) + SMALLC;
        p[c] += raw1;
      }
    }
    block_fold16(p, wbuf, cbuf, lane, wv, tid);
  }

  // ---- warm start x_r = <b, weight2[r,:]> ----
  {
    float p[K1];
    float tkr[KK], colr[KK];
    #pragma unroll
    for (int c = 0; c < KK; ++c){ tkr[c] = tk[c]; colr[c] = cbuf[c]; }
    #pragma unroll
    for (int c = 0; c < K1; ++c) p[c] = 0.0f;
    #pragma unroll
    for (int j = 0; j < RPT; ++j){
      int i = tid + NT * j;
      float si = scratch[i];
      float bb[K1];
      float rowpart = 0.0f;
      #pragma unroll
      for (int c = 0; c < KK; ++c){
        float d = si - (float)(KK - c);
        float Cc = d * d * cinv;
        float z = fabsf(tkr[c] - si) / tauv;
        float raw1 = 1.0f / (1.0f + expf(z)) + SMALLC;
        float g0 = (raw1 / colr[c]) * inv_n;
        rowpart += g0;
        bb[c] = Cc + EPSI * logf(g0);
      }
      {
        float Cc = si * si * cinv;  // anchor 0 for c=15
        float g0l = fminf(fmaxf(inv_n - rowpart, SMALLC), 1.0f - SMALLC);
        bb[KK] = Cc + EPSI * logf(g0l);
      }
      #pragma unroll
      for (int r = 0; r < 5; ++r){
        const float4* wp = (const float4*)(w2 + (size_t)r * W2STRIDE + (size_t)i * K1);
        float4 a0 = wp[0], a1 = wp[1], a2 = wp[2], a3 = wp[3];
        float acc = p[r];
        acc += bb[0] * a0.x + bb[1] * a0.y + bb[2] * a0.z + bb[3] * a0.w;
        acc += bb[4] * a1.x + bb[5] * a1.y + bb[6] * a1.z + bb[7] * a1.w;
        acc += bb[8] * a2.x + bb[9] * a2.y + bb[10] * a2.z + bb[11] * a2.w;
        acc += bb[12] * a3.x + bb[13] * a3.y + bb[14] * a3.z + bb[15] * a3.w;
        p[r] = acc;
      }
    }
    block_fold16(p, wbuf, xbuf, lane, wv, tid);
  }

  // ---- vt init: vt_c = B_c * exp(g_c/eps); vt[15] = 1 ----
  float vt[K1];
  {
    float xv[5];
    #pragma unroll
    for (int r = 0; r < 5; ++r) xv[r] = xbuf[r];
    #pragma unroll
    for (int c = 0; c < KK; ++c){
      float g = 0.0f;
      #pragma unroll
      for (int r = 0; r < 5; ++r) g += xv[r] * w1[(size_t)(NN + c) * 5 + r];
      float Bc = expf(-10.0f * cinv * (float)((KK - c) * (KK - c)));
      vt[c] = Bc * expf(g * 10.0f);
    }
    vt[KK] = 1.0f;
  }

  // ---- x per row pair + iteration-invariant power table xp[q][c] = x^c ----
  f2 x2[NPAIR];
  #pragma unroll
  for (int q = 0; q < NPAIR; ++q){
    float s0 = scratch[tid + NT * (2 * q)];
    float s1 = scratch[tid + NT * (2 * q + 1)];
    x2[q].x = expf(s0 * (-20.0f * cinv));
    x2[q].y = expf(s1 * (-20.0f * cinv));
  }
  f2 xp[NPAIR][K1];
  #pragma unroll
  for (int q = 0; q < NPAIR; ++q){
    xp[q][0].x = 1.0f; xp[q][0].y = 1.0f;
    xp[q][1] = x2[q];
    #pragma unroll
    for (int c = 2; c < K1; ++c) xp[q][c] = xp[q][c - 1] * x2[q];
  }

  // ---- Sinkhorn: barrier-free asynchronous iterations ----
  // Each wave posts its 16 col-partials to slot [wv] of wbufT[0] and reads all
  // 8 slots volatile (tolerating <=1-iter staleness: chaotic relaxation on a
  // contraction converges to the same fixed point; warm start => small drift).
  // Per-wave convergence exit; no barrier in the loop => no convoy.
  f2 t2[NPAIR];
  const float nmul = ((lane & 15) < KK) ? 1.0f : 4081.0f;  // nu_c * NN
  float wprev = -1.0e30f;   // lanes<16: previous vt[lane]

  // iter 0: post own partial so every slot is initialized, then one barrier
  {
    float r = iter_math(vt, x2, xp, t2, lane);
    if (lane < 16) wbufT[0][fold_col(lane) * TS + wv] = r;
  }
  __syncthreads();

  #pragma unroll 1
  for (int it = 0; it < NITER; ++it){
    float md = -1.0f;
    float wnew = 0.0f;
    if (lane < 16){
      volatile const float* wp = &wbufT[0][lane * TS];
      float s0 = wp[0], s1 = wp[1], s2 = wp[2], s3 = wp[3];
      float s4 = wp[4], s5 = wp[5], s6 = wp[6], s7 = wp[7];
      float t = ((s0 + s1) + (s2 + s3)) + ((s4 + s5) + (s6 + s7));
      wnew = nmul * __builtin_amdgcn_rcpf(t);
      md = fabsf(wnew - wprev) - CONV_REL * wprev;
      wprev = wnew;
    }
    int conv = __all(md <= 0.0f);        // per-wave decision (wave-scope)
    #pragma unroll
    for (int c = 0; c < K1; ++c)
      vt[c] = __uint_as_float((unsigned)__builtin_amdgcn_readlane(
                  (int)__float_as_uint(wnew), c));
    if (conv) break;
    float r = iter_math(vt, x2, xp, t2, lane);
    if (lane < 16) wbufT[0][fold_col(lane) * TS + wv] = r;
  }

  // ---- 2 synchronized polish iterations: restore block-uniform vt + t2 ----
  __syncthreads();
  #pragma unroll 1
  for (int pp = 0; pp < 2; ++pp){
    const int bsel = pp ^ 1;             // pp0 -> buf1, pp1 -> buf0 (both free)
    float r = iter_math(vt, x2, xp, t2, lane);
    if (lane < 16) wbufT[bsel][fold_col(lane) * TS + wv] = r;
    __syncthreads();
    float wnew = 0.0f;
    if (lane < 16){
      const float* wp = &wbufT[bsel][lane * TS];
      float4 a4 = *(const float4*)wp;
      float4 b4 = *(const float4*)(wp + 4);
      float t = ((a4.x + a4.y) + (a4.z + a4.w)) + ((b4.x + b4.y) + (b4.z + b4.w));
      wnew = nmul * __builtin_amdgcn_rcpf(t);
    }
    #pragma unroll
    for (int c = 0; c < K1; ++c)
      vt[c] = __uint_as_float((unsigned)__builtin_amdgcn_readlane(
                  (int)__float_as_uint(wnew), c));
  }

  // ---- epilogue: Gamma = x^c * (inv_n*t) * vt; A = Gamma[:,:,:15]*n; norm^2 ----
  float nrm = 0.0f;
  {
    float tkr[KK], colr[KK];
    #pragma unroll
    for (int c = 0; c < KK; ++c){ tkr[c] = tk[c]; colr[c] = cbuf[c]; }
    #pragma unroll
    for (int q = 0; q < NPAIR; ++q){
      // element x: row j = 2q
      {
        int i = tid + NT * (2 * q);
        float si = scratch[i];
        float xj = x2[q].x;
        float pw = t2[q].x * inv_n;
        float rowpart = 0.0f;
        float* op = out + (size_t)(b * NN + i) * KK;
        #pragma unroll
        for (int c = 0; c < KK; ++c){
          float gam = pw * vt[c];
          pw *= xj;
          float z = fabsf(tkr[c] - si) / tauv;
          float raw1 = 1.0f / (1.0f + expf(z)) + SMALLC;
          float g0 = (raw1 / colr[c]) * inv_n;
          rowpart += g0;
          float d = gam - g0;
          nrm += d * d;
          op[c] = gam * (float)NN;
        }
        {
          float gam = pw * vt[KK];
          float g0l = fminf(fmaxf(inv_n - rowpart, SMALLC), 1.0f - SMALLC);
          float d = gam - g0l;
          nrm += d * d;
        }
      }
      // element y: row j = 2q+1
      {
        int i = tid + NT * (2 * q + 1);
        float si = scratch[i];
        float xj = x2[q].y;
        float pw = t2[q].y * inv_n;
        float rowpart = 0.0f;
        float* op = out + (size_t)(b * NN + i) * KK;
        #pragma unroll
        for (int c = 0; c < KK; ++c){
          float gam = pw * vt[c];
          pw *= xj;
          float z = fabsf(tkr[c] - si) / tauv;
          float raw1 = 1.0f / (1.0f + expf(z)) + SMALLC;
          float g0 = (raw1 / colr[c]) * inv_n;
          rowpart += g0;
          float d = gam - g0;
          nrm += d * d;
          op[c] = gam * (float)NN;
        }
        {
          float gam = pw * vt[KK];
          float g0l = fminf(fmaxf(inv_n - rowpart, SMALLC), 1.0f - SMALLC);
          float d = gam - g0l;
          nrm += d * d;
        }
      }
    }
  }
  #pragma unroll
  for (int off = 32; off; off >>= 1) nrm += __shfl_xor(nrm, off);
  if (lane == 0) rv[wv] = nrm;
  __syncthreads();
  if (tid == 0){
    float t = 0.0f;
    for (int q = 0; q < NW; ++q) t += rv[q];
    atomicAdd(reinterpret_cast<float*>(ws) + 2, t);
    __threadfence();
    unsigned prev = atomicAdd(&ws[4], 1u);
    if (prev == (unsigned)(BSZ - 1)){
      float n2 = __hip_atomic_load(reinterpret_cast<float*>(ws) + 2,
                                   __ATOMIC_RELAXED, __HIP_MEMORY_SCOPE_AGENT);
      out[OUT_A_ELEMS] = sqrtf(n2);
    }
  }
}

extern "C" void kernel_launch(void* const* d_in, const int* in_sizes, int n_in,
                              void* d_out, int out_size, void* d_ws, size_t ws_size,
                              hipStream_t stream){
  const float* scores = (const float*)d_in[0];
  const float* tau    = (const float*)d_in[1];
  const float* w1     = (const float*)d_in[2];  // (4111, 5) row-major
  const float* w2     = (const float*)d_in[3];  // (5, 65536) row-major
  float* out = (float*)d_out;
  unsigned* ws = (unsigned*)d_ws;

  // [0]=max_enc 0, [1]=neg 0, [2]=norm 0.f, [3]=arrive 0, [4]=done 0, [5]=min_enc FF
  hipMemsetAsync(ws, 0x00, 20, stream);
  hipMemsetAsync((char*)ws + 20, 0xFF, 4, stream);

  k_main<<<BSZ, NT, 0, stream>>>(scores, tau, w1, w2, out, ws);
}

// Round 5
// 154.888 us; speedup vs baseline: 1.2923x; 1.2923x over previous
//
#include <hip/hip_runtime.h>
#include <math.h>

#define KK 15
#define K1 16
#define NN 4096
#define BSZ 128
#define NT 512
#define RPT 8          // rows per thread = NN/NT
#define NPAIR 4        // packed row pairs per thread
#define NW 8           // waves per block
#define EPSI 0.1f
#define SMALLC 1e-20f
#define NITER 200
#define W2STRIDE 65536
#define OUT_A_ELEMS (BSZ * NN * KK)
#define TS 20          // wbufT row stride in floats (2-way bank alias only, free)
#define CONV_REL 5e-7f

typedef __attribute__((ext_vector_type(2))) float f2;
typedef __attribute__((ext_vector_type(2))) unsigned u2v;
__device__ __forceinline__ f2 pk_fma(f2 a, f2 b, f2 c){
  return __builtin_elementwise_fma(a, b, c);
}

// ---------- sortable float <-> uint encoding for atomic min/max ----------
__device__ __forceinline__ unsigned enc_f32(float f){
  unsigned u = __float_as_uint(f);
  return (u & 0x80000000u) ? ~u : (u | 0x80000000u);
}
__device__ __forceinline__ float dec_f32(unsigned e){
  unsigned u = (e & 0x80000000u) ? (e ^ 0x80000000u) : ~e;
  return __uint_as_float(u);
}

// ws layout (uint32): [0]=max_enc(0) [1]=neg_flag(0) [2]=norm^2 f32(0)
//                     [3]=arrive(0) [4]=done(0) [5]=min_enc(0xFFFFFFFF)

// ---------- DPP cross-lane mov (VALU pipe, not DS) ----------
template<int CTRL>
__device__ __forceinline__ float dpp_movf(float x){
  return __uint_as_float((unsigned)__builtin_amdgcn_update_dpp(
      (int)0, (int)__float_as_uint(x), CTRL, 0xF, 0xF, true));
}

// xor16 / xor32 sums via permlane swaps (VALU pipe); shfl fallback if builtin missing
__device__ __forceinline__ float xsum16(float r){
#if __has_builtin(__builtin_amdgcn_permlane16_swap)
  u2v s = __builtin_amdgcn_permlane16_swap(__float_as_uint(r), __float_as_uint(r), false, false);
  return __uint_as_float(s.x) + __uint_as_float(s.y);
#else
  return r + __shfl_xor(r, 16);
#endif
}
__device__ __forceinline__ float xsum32(float r){
#if __has_builtin(__builtin_amdgcn_permlane32_swap)
  u2v s = __builtin_amdgcn_permlane32_swap(__float_as_uint(r), __float_as_uint(r), false, false);
  return __uint_as_float(s.x) + __uint_as_float(s.y);
#else
  return r + __shfl_xor(r, 32);
#endif
}

// ---------- 16-column lane-fold reduction (DPP-based) ----------
// Stage masks: 1 (quad_perm), 2 (quad_perm), 8 (row_ror:8), 4 (ds shfl), then
// xor16/xor32 permlane sums. Column bit assignment: b3<-l&1, b2<-l&2, b1<-l&8, b0<-l&4.
__device__ __forceinline__ int fold_col(int lane){
  int l = lane & 15;
  return ((l & 1) << 3) | ((l & 2) << 1) | ((l & 8) >> 2) | ((l & 4) >> 2);
}

__device__ __forceinline__ float wave_fold16(const float p[K1], int lane){
  float a[8];
  {
    const bool hi = (lane & 1) != 0;
    #pragma unroll
    for (int j = 0; j < 8; ++j){
      float send = hi ? p[j] : p[j + 8];
      float keep = hi ? p[j + 8] : p[j];
      a[j] = keep + dpp_movf<0xB1>(send);       // quad_perm [1,0,3,2] == xor1
    }
  }
  float bq[4];
  {
    const bool hi = (lane & 2) != 0;
    #pragma unroll
    for (int j = 0; j < 4; ++j){
      float send = hi ? a[j] : a[j + 4];
      float keep = hi ? a[j + 4] : a[j];
      bq[j] = keep + dpp_movf<0x4E>(send);      // quad_perm [2,3,0,1] == xor2
    }
  }
  float cq[2];
  {
    const bool hi = (lane & 8) != 0;
    float s0 = hi ? bq[0] : bq[2];
    float s1 = hi ? bq[1] : bq[3];
    float k0 = hi ? bq[2] : bq[0];
    float k1 = hi ? bq[3] : bq[1];
    cq[0] = k0 + dpp_movf<0x128>(s0);           // row_ror:8 == xor8 within 16
    cq[1] = k1 + dpp_movf<0x128>(s1);
  }
  float r;
  {
    const bool hi = (lane & 4) != 0;
    float send = hi ? cq[0] : cq[1];
    float keep = hi ? cq[1] : cq[0];
    r = keep + __shfl_xor(send, 4);             // the one remaining DS op
  }
  r = xsum16(r);
  r = xsum32(r);
  return r;
}

__device__ __forceinline__ void block_fold16(const float p[K1], float* wb, float* tb,
                                             int lane, int wv, int tid){
  float r = wave_fold16(p, lane);
  if (lane < 16) wb[wv * K1 + fold_col(lane)] = r;
  __syncthreads();
  if (tid < 16){
    float t = 0.0f;
    #pragma unroll
    for (int q = 0; q < NW; ++q) t += wb[q * K1 + tid];
    tb[tid] = t;
  }
  __syncthreads();
}

__global__ __launch_bounds__(NT, 2) void k_main(
    const float* __restrict__ scores, const float* __restrict__ taup,
    const float* __restrict__ w1, const float* __restrict__ w2,
    float* __restrict__ out, unsigned* __restrict__ ws){
  const int b = blockIdx.x;
  const int tid = threadIdx.x;
  const int lane = tid & 63;
  const int wv = tid >> 6;

  __shared__ float scratch[NN];
  __shared__ float tk[KK];
  __shared__ int tki[KK];
  __shared__ __align__(16) float cbuf[K1];
  __shared__ float wbuf[NW * K1];
  __shared__ __align__(16) float xbuf[K1];
  __shared__ __align__(16) float wbufT[2][K1 * TS];
  __shared__ float rv[NW];
  __shared__ int ri[NW];
  __shared__ float rmn[NW];
  __shared__ unsigned sng[NW];
  __shared__ float statb[4];

  // ---- load raw row ----
  float raw[RPT];
  #pragma unroll
  for (int j = 0; j < RPT; ++j) raw[j] = scores[(size_t)b * NN + tid + NT * j];

  // ---- fused global min/max/neg + device spin-barrier ----
  {
    float mx = -INFINITY, mn = INFINITY; unsigned neg = 0u;
    #pragma unroll
    for (int j = 0; j < RPT; ++j){
      float v = raw[j];
      mx = fmaxf(mx, v);
      if (v == -INFINITY) neg = 1u; else mn = fminf(mn, v);
    }
    #pragma unroll
    for (int off = 32; off; off >>= 1){
      mx = fmaxf(mx, __shfl_xor(mx, off));
      mn = fminf(mn, __shfl_xor(mn, off));
      neg |= (unsigned)__shfl_xor((int)neg, off);
    }
    if (lane == 0){ rv[wv] = mx; rmn[wv] = mn; sng[wv] = neg; }
    __syncthreads();
    if (tid == 0){
      for (int q = 1; q < NW; ++q){
        mx = fmaxf(mx, rv[q]); mn = fminf(mn, rmn[q]); neg |= sng[q];
      }
      atomicMax(&ws[0], enc_f32(mx));
      atomicMin(&ws[5], enc_f32(mn));
      if (neg) atomicOr(&ws[1], 1u);
      __threadfence();
      atomicAdd(&ws[3], 1u);
      while (__hip_atomic_load(&ws[3], __ATOMIC_ACQUIRE, __HIP_MEMORY_SCOPE_AGENT) < (unsigned)BSZ)
        __builtin_amdgcn_s_sleep(2);
      statb[0] = dec_f32(__hip_atomic_load(&ws[0], __ATOMIC_RELAXED, __HIP_MEMORY_SCOPE_AGENT));
      statb[1] = dec_f32(__hip_atomic_load(&ws[5], __ATOMIC_RELAXED, __HIP_MEMORY_SCOPE_AGENT));
      statb[2] = __hip_atomic_load(&ws[1], __ATOMIC_RELAXED, __HIP_MEMORY_SCOPE_AGENT) ? 1.0f : 0.0f;
    }
    __syncthreads();
  }

  const float smax = statb[0];
  const float smin_raw = statb[1];
  const bool has_neg = statb[2] != 0.0f;
  const float filled = smin_raw - (smax - smin_raw);
  const float smin_eff = has_neg ? filled : smin_raw;
  const float cmax = fmaxf(fmaxf(smin_eff * smin_eff, smax * smax),
                           fmaxf((smin_eff - 15.0f) * (smin_eff - 15.0f),
                                 (smax - 15.0f) * (smax - 15.0f)));
  const float cinv = 1.0f / cmax;
  const float tauv = taup[0];
  const float invtau = 1.0f / tauv;       // exact divide, once
  const float inv_n = 1.0f / (float)NN;   // 2^-12, exact

  // ---- fixed s values into scratch (also used for top-k) ----
  #pragma unroll
  for (int j = 0; j < RPT; ++j){
    float v = raw[j]; if (v == -INFINITY) v = filled;
    scratch[tid + NT * j] = v;
  }
  __syncthreads();

  // ---- top-15 by iterative argmax (record indices for restore) ----
  for (int t = 0; t < KK; ++t){
    float bv = -INFINITY; int bi = NN;
    #pragma unroll
    for (int j = 0; j < RPT; ++j){
      int i = tid + NT * j;
      float v = scratch[i];
      if (v > bv){ bv = v; bi = i; }
    }
    #pragma unroll
    for (int off = 32; off; off >>= 1){
      float ov = __shfl_xor(bv, off);
      int oi = __shfl_xor(bi, off);
      if (ov > bv || (ov == bv && oi < bi)){ bv = ov; bi = oi; }
    }
    if (lane == 0){ rv[wv] = bv; ri[wv] = bi; }
    __syncthreads();
    if (tid == 0){
      for (int q = 1; q < NW; ++q){
        if (rv[q] > bv || (rv[q] == bv && ri[q] < bi)){ bv = rv[q]; bi = ri[q]; }
      }
      tk[t] = bv;
      tki[t] = bi;
      scratch[bi] = -INFINITY;
    }
    __syncthreads();
  }
  // restore the 15 extracted values so scratch holds the full filled s row
  if (tid < KK) scratch[tki[tid]] = tk[tid];
  __syncthreads();

  // ---- Gamma0 column sums (fast sigmoid: rcp + native exp; feeds colr/warm/nrm only) ----
  {
    float p[K1];
    float tkr[KK];
    #pragma unroll
    for (int c = 0; c < KK; ++c) tkr[c] = tk[c];
    #pragma unroll
    for (int c = 0; c < K1; ++c) p[c] = 0.0f;
    #pragma unroll
    for (int j = 0; j < RPT; ++j){
      float si = scratch[tid + NT * j];
      #pragma unroll
      for (int c = 0; c < KK; ++c){
        float z = fabsf(tkr[c] - si) * invtau;
        float raw1 = __builtin_amdgcn_rcpf(1.0f + __expf(z)) + SMALLC;
        p[c] += raw1;
      }
    }
    block_fold16(p, wbuf, cbuf, lane, wv, tid);
  }

  // ---- warm start x_r = <b, weight2[r,:]> ----
  float colinv_n[KK];   // (1/colsum_c) * inv_n, reused in epilogue
  {
    float p[K1];
    float tkr[KK];
    #pragma unroll
    for (int c = 0; c < KK; ++c){
      tkr[c] = tk[c];
      colinv_n[c] = (1.0f / cbuf[c]) * inv_n;   // exact divide, once per c
    }
    #pragma unroll
    for (int c = 0; c < K1; ++c) p[c] = 0.0f;
    #pragma unroll
    for (int j = 0; j < RPT; ++j){
      int i = tid + NT * j;
      float si = scratch[i];
      float bb[K1];
      float rowpart = 0.0f;
      #pragma unroll
      for (int c = 0; c < KK; ++c){
        float d = si - (float)(KK - c);
        float Cc = d * d * cinv;
        float z = fabsf(tkr[c] - si) * invtau;
        float raw1 = __builtin_amdgcn_rcpf(1.0f + __expf(z)) + SMALLC;
        float g0 = raw1 * colinv_n[c];
        rowpart += g0;
        bb[c] = Cc + EPSI * __logf(g0);
      }
      {
        float Cc = si * si * cinv;  // anchor 0 for c=15
        float g0l = fminf(fmaxf(inv_n - rowpart, SMALLC), 1.0f - SMALLC);
        bb[KK] = Cc + EPSI * __logf(g0l);
      }
      #pragma unroll
      for (int r = 0; r < 5; ++r){
        const float4* wp = (const float4*)(w2 + (size_t)r * W2STRIDE + (size_t)i * K1);
        float4 a0 = wp[0], a1 = wp[1], a2 = wp[2], a3 = wp[3];
        float acc = p[r];
        acc += bb[0] * a0.x + bb[1] * a0.y + bb[2] * a0.z + bb[3] * a0.w;
        acc += bb[4] * a1.x + bb[5] * a1.y + bb[6] * a1.z + bb[7] * a1.w;
        acc += bb[8] * a2.x + bb[9] * a2.y + bb[10] * a2.z + bb[11] * a2.w;
        acc += bb[12] * a3.x + bb[13] * a3.y + bb[14] * a3.z + bb[15] * a3.w;
        p[r] = acc;
      }
    }
    block_fold16(p, wbuf, xbuf, lane, wv, tid);
  }

  // ---- vt init: vt_c = B_c * exp(g_c/eps); vt[15] = 1 ----
  float vt[K1];
  {
    float xv[5];
    #pragma unroll
    for (int r = 0; r < 5; ++r) xv[r] = xbuf[r];
    #pragma unroll
    for (int c = 0; c < KK; ++c){
      float g = 0.0f;
      #pragma unroll
      for (int r = 0; r < 5; ++r) g += xv[r] * w1[(size_t)(NN + c) * 5 + r];
      float Bc = expf(-10.0f * cinv * (float)((KK - c) * (KK - c)));
      vt[c] = Bc * expf(g * 10.0f);
    }
    vt[KK] = 1.0f;
  }

  // ---- x per row pair + iteration-invariant power table xp[q][c] = x^c ----
  // (x2/xp define the kernel matrix -> keep exact expf path)
  f2 x2[NPAIR];
  #pragma unroll
  for (int q = 0; q < NPAIR; ++q){
    float s0 = scratch[tid + NT * (2 * q)];
    float s1 = scratch[tid + NT * (2 * q + 1)];
    x2[q].x = expf(s0 * (-20.0f * cinv));
    x2[q].y = expf(s1 * (-20.0f * cinv));
  }
  f2 xp[NPAIR][K1];
  #pragma unroll
  for (int q = 0; q < NPAIR; ++q){
    xp[q][0].x = 1.0f; xp[q][0].y = 1.0f;
    xp[q][1] = x2[q];
    #pragma unroll
    for (int c = 2; c < K1; ++c) xp[q][c] = xp[q][c - 1] * x2[q];
  }

  // ---- Sinkhorn: synchronized loop + guarded component-wise Steffensen ----
  // Plain sweep: t_j = 1/sum_c vt_c x^c; wnew_c = nu_c*NN / sum_j t_j x^c.
  // Every 2 plain applied steps, Aitken d2/(d2-d1) jump per component (lane<16),
  // guarded: contraction evidence, positive bracket, min step. Jump cannot fire
  // on the exit iteration (md<=0 => |d2| below min-step guard), so the epilogue
  // (t2, vt) pairing stays plain-consistent, matching the reference structure.
  f2 t2[NPAIR];
  const float nmul = ((lane & 15) < KK) ? 1.0f : 4081.0f;  // nu_c * NN
  float pv2 = 0.0f, pv1 = 0.0f;  // last-two APPLIED values (lanes<16)
  int pcnt = -1;                 // consecutive plain applied steps since jump
  #pragma unroll 1
  for (int it = 0; it < NITER; ++it){
    const int ph = it & 1;
    // row sums: h_j = sum_c vt[c] * x_j^c (Horner; 4 independent chains)
    #pragma unroll
    for (int q = 0; q < NPAIR; ++q){
      f2 h; h.x = vt[KK]; h.y = vt[KK];
      #pragma unroll
      for (int c = KK - 1; c >= 0; --c){
        f2 vc; vc.x = vt[c]; vc.y = vt[c];
        h = pk_fma(h, x2[q], vc);
      }
      t2[q].x = __builtin_amdgcn_rcpf(h.x);
      t2[q].y = __builtin_amdgcn_rcpf(h.y);
    }
    // col partials: p[c] = sum_j t_j * x_j^c (independent fmas via power table)
    float p[K1];
    #pragma unroll
    for (int c = 0; c < K1; ++c){
      f2 s = t2[0] * xp[0][c];
      #pragma unroll
      for (int q = 1; q < NPAIR; ++q) s = pk_fma(t2[q], xp[q][c], s);
      p[c] = s.x + s.y;
    }
    float r = wave_fold16(p, lane);
    if (lane < 16) wbufT[ph][fold_col(lane) * TS + wv] = r;
    __syncthreads();
    float md = -1.0f;
    float wout = 0.0f;
    if (lane < 16){
      const float* wp = &wbufT[ph][lane * TS];
      float4 a4 = *(const float4*)wp;
      float4 b4 = *(const float4*)(wp + 4);
      float t = ((a4.x + a4.y) + (a4.z + a4.w)) + ((b4.x + b4.y) + (b4.z + b4.w));
      float wnew = nmul * __builtin_amdgcn_rcpf(t);
      md = fabsf(wnew - pv1) - CONV_REL * pv1;
      wout = wnew;
      if (pcnt >= 1){
        float d1 = pv1 - pv2;
        float d2 = wnew - pv1;
        float den = d2 - d1;
        float acc = wnew - d2 * d2 * __builtin_amdgcn_rcpf(den);
        bool ok = (fabsf(d2) < fabsf(d1)) &&
                  (acc > 0.1f * wnew) && (acc < 10.0f * wnew) &&
                  (fabsf(d2) > 4.0f * CONV_REL * wnew);
        if (ok){ wout = acc; pcnt = -1; }
      }
      pcnt++;
      pv2 = pv1; pv1 = wout;
    }
    // identical data in every wave -> identical decisions -> uniform exit
    int conv = __all(md <= 0.0f);
    #pragma unroll
    for (int c = 0; c < K1; ++c)
      vt[c] = __uint_as_float((unsigned)__builtin_amdgcn_readlane(
                  (int)__float_as_uint(wout), c));
    if (conv) break;
  }

  // ---- epilogue: Gamma = x^c * (inv_n*t) * vt; A = Gamma[:,:,:15]*n; norm^2 ----
  float nrm = 0.0f;
  {
    float tkr[KK];
    #pragma unroll
    for (int c = 0; c < KK; ++c) tkr[c] = tk[c];
    #pragma unroll
    for (int q = 0; q < NPAIR; ++q){
      #pragma unroll
      for (int half = 0; half < 2; ++half){
        int i = tid + NT * (2 * q + half);
        float si = scratch[i];
        float tin = (half ? t2[q].y : t2[q].x) * inv_n;
        float rowpart = 0.0f;
        float gamv[KK];
        float gaml;
        #pragma unroll
        for (int c = 0; c < KK; ++c){
          float xc = half ? xp[q][c].y : xp[q][c].x;
          float gam = (tin * xc) * vt[c];
          float z = fabsf(tkr[c] - si) * invtau;
          float raw1 = __builtin_amdgcn_rcpf(1.0f + __expf(z)) + SMALLC;
          float g0 = raw1 * colinv_n[c];
          rowpart += g0;
          float d = gam - g0;
          nrm += d * d;
          gamv[c] = gam * (float)NN;
        }
        {
          float xc = half ? xp[q][KK].y : xp[q][KK].x;
          gaml = (tin * xc) * vt[KK];
          float g0l = fminf(fmaxf(inv_n - rowpart, SMALLC), 1.0f - SMALLC);
          float d = gaml - g0l;
          nrm += d * d;
        }
        float* op = out + (size_t)(b * NN + i) * KK;
        #pragma unroll
        for (int c = 0; c < KK; ++c) op[c] = gamv[c];   // adjacent -> merged stores
      }
    }
  }
  #pragma unroll
  for (int off = 32; off; off >>= 1) nrm += __shfl_xor(nrm, off);
  if (lane == 0) rv[wv] = nrm;
  __syncthreads();
  if (tid == 0){
    float t = 0.0f;
    for (int q = 0; q < NW; ++q) t += rv[q];
    atomicAdd(reinterpret_cast<float*>(ws) + 2, t);
    __threadfence();
    unsigned prev = atomicAdd(&ws[4], 1u);
    if (prev == (unsigned)(BSZ - 1)){
      float n2 = __hip_atomic_load(reinterpret_cast<float*>(ws) + 2,
                                   __ATOMIC_RELAXED, __HIP_MEMORY_SCOPE_AGENT);
      out[OUT_A_ELEMS] = sqrtf(n2);
    }
  }
}

extern "C" void kernel_launch(void* const* d_in, const int* in_sizes, int n_in,
                              void* d_out, int out_size, void* d_ws, size_t ws_size,
                              hipStream_t stream){
  const float* scores = (const float*)d_in[0];
  const float* tau    = (const float*)d_in[1];
  const float* w1     = (const float*)d_in[2];  // (4111, 5) row-major
  const float* w2     = (const float*)d_in[3];  // (5, 65536) row-major
  float* out = (float*)d_out;
  unsigned* ws = (unsigned*)d_ws;

  // [0]=max_enc 0, [1]=neg 0, [2]=norm 0.f, [3]=arrive 0, [4]=done 0, [5]=min_enc FF
  hipMemsetAsync(ws, 0x00, 20, stream);
  hipMemsetAsync((char*)ws + 20, 0xFF, 4, stream);

  k_main<<<BSZ, NT, 0, stream>>>(scores, tau, w1, w2, out, ws);
}

// Round 6
// 150.475 us; speedup vs baseline: 1.3302x; 1.0293x over previous
//
#include <hip/hip_runtime.h>
#include <math.h>

#define KK 15
#define K1 16
#define NN 4096
#define BSZ 128
#define NT 512
#define RPT 8          // rows per thread = NN/NT
#define NPAIR 4        // packed row pairs per thread
#define NW 8           // waves per block
#define EPSI 0.1f
#define SMALLC 1e-20f
#define NITER 200
#define W2STRIDE 65536
#define OUT_A_ELEMS (BSZ * NN * KK)
#define TS 20          // wbufT row stride in floats (2-way bank alias only, free)
#define CONV_REL 5e-7f

typedef __attribute__((ext_vector_type(2))) float f2;
typedef __attribute__((ext_vector_type(2))) unsigned u2v;
__device__ __forceinline__ f2 pk_fma(f2 a, f2 b, f2 c){
  return __builtin_elementwise_fma(a, b, c);
}

// ---------- sortable float <-> uint encoding for atomic min/max ----------
__device__ __forceinline__ unsigned enc_f32(float f){
  unsigned u = __float_as_uint(f);
  return (u & 0x80000000u) ? ~u : (u | 0x80000000u);
}
__device__ __forceinline__ float dec_f32(unsigned e){
  unsigned u = (e & 0x80000000u) ? (e ^ 0x80000000u) : ~e;
  return __uint_as_float(u);
}

// ws layout (uint32): [0]=max_enc(0) [1]=neg_flag(0) [2]=norm^2 f32(0)
//                     [3]=arrive(0) [4]=done(0) [5]=min_enc(0xFFFFFFFF)

// ---------- DPP cross-lane mov (VALU pipe, not DS) ----------
template<int CTRL>
__device__ __forceinline__ float dpp_movf(float x){
  return __uint_as_float((unsigned)__builtin_amdgcn_update_dpp(
      (int)0, (int)__float_as_uint(x), CTRL, 0xF, 0xF, true));
}

__device__ __forceinline__ float bcast_lane0(float x){
  return __uint_as_float((unsigned)__builtin_amdgcn_readlane(
      (int)__float_as_uint(x), 0));
}

// xor16 / xor32 sums via permlane swaps (VALU pipe); shfl fallback if builtin missing
__device__ __forceinline__ float xsum16(float r){
#if __has_builtin(__builtin_amdgcn_permlane16_swap)
  u2v s = __builtin_amdgcn_permlane16_swap(__float_as_uint(r), __float_as_uint(r), false, false);
  return __uint_as_float(s.x) + __uint_as_float(s.y);
#else
  return r + __shfl_xor(r, 16);
#endif
}
__device__ __forceinline__ float xsum32(float r){
#if __has_builtin(__builtin_amdgcn_permlane32_swap)
  u2v s = __builtin_amdgcn_permlane32_swap(__float_as_uint(r), __float_as_uint(r), false, false);
  return __uint_as_float(s.x) + __uint_as_float(s.y);
#else
  return r + __shfl_xor(r, 32);
#endif
}

// full 16-lane sum (valid in lanes 0..15 of each 16-row) -- 4 DPP adds, no DS
__device__ __forceinline__ float sum16_all(float v){
  v += dpp_movf<0x128>(v);   // row_ror:8
  v += dpp_movf<0x124>(v);   // row_ror:4
  v += dpp_movf<0x4E>(v);    // quad_perm xor2
  v += dpp_movf<0xB1>(v);    // quad_perm xor1
  return v;
}

// ---------- 16-column lane-fold reduction (DPP-based) ----------
// Stage masks: 1 (quad_perm), 2 (quad_perm), 8 (row_ror:8), 4 (ds shfl), then
// xor16/xor32 permlane sums. Column bit assignment: b3<-l&1, b2<-l&2, b1<-l&8, b0<-l&4.
__device__ __forceinline__ int fold_col(int lane){
  int l = lane & 15;
  return ((l & 1) << 3) | ((l & 2) << 1) | ((l & 8) >> 2) | ((l & 4) >> 2);
}

__device__ __forceinline__ float wave_fold16(const float p[K1], int lane){
  float a[8];
  {
    const bool hi = (lane & 1) != 0;
    #pragma unroll
    for (int j = 0; j < 8; ++j){
      float send = hi ? p[j] : p[j + 8];
      float keep = hi ? p[j + 8] : p[j];
      a[j] = keep + dpp_movf<0xB1>(send);       // quad_perm [1,0,3,2] == xor1
    }
  }
  float bq[4];
  {
    const bool hi = (lane & 2) != 0;
    #pragma unroll
    for (int j = 0; j < 4; ++j){
      float send = hi ? a[j] : a[j + 4];
      float keep = hi ? a[j + 4] : a[j];
      bq[j] = keep + dpp_movf<0x4E>(send);      // quad_perm [2,3,0,1] == xor2
    }
  }
  float cq[2];
  {
    const bool hi = (lane & 8) != 0;
    float s0 = hi ? bq[0] : bq[2];
    float s1 = hi ? bq[1] : bq[3];
    float k0 = hi ? bq[2] : bq[0];
    float k1 = hi ? bq[3] : bq[1];
    cq[0] = k0 + dpp_movf<0x128>(s0);           // row_ror:8 == xor8 within 16
    cq[1] = k1 + dpp_movf<0x128>(s1);
  }
  float r;
  {
    const bool hi = (lane & 4) != 0;
    float send = hi ? cq[0] : cq[1];
    float keep = hi ? cq[1] : cq[0];
    r = keep + __shfl_xor(send, 4);             // the one remaining DS op
  }
  r = xsum16(r);
  r = xsum32(r);
  return r;
}

__device__ __forceinline__ void block_fold16(const float p[K1], float* wb, float* tb,
                                             int lane, int wv, int tid){
  float r = wave_fold16(p, lane);
  if (lane < 16) wb[wv * K1 + fold_col(lane)] = r;
  __syncthreads();
  if (tid < 16){
    float t = 0.0f;
    #pragma unroll
    for (int q = 0; q < NW; ++q) t += wb[q * K1 + tid];
    tb[tid] = t;
  }
  __syncthreads();
}

__global__ __launch_bounds__(NT, 2) void k_main(
    const float* __restrict__ scores, const float* __restrict__ taup,
    const float* __restrict__ w1, const float* __restrict__ w2,
    float* __restrict__ out, unsigned* __restrict__ ws){
  const int b = blockIdx.x;
  const int tid = threadIdx.x;
  const int lane = tid & 63;
  const int wv = tid >> 6;

  __shared__ float scratch[NN];
  __shared__ float tk[KK];
  __shared__ int tki[KK];
  __shared__ __align__(16) float cbuf[K1];
  __shared__ float wbuf[NW * K1];
  __shared__ __align__(16) float xbuf[K1];
  __shared__ __align__(16) float wbufT[2][K1 * TS];
  __shared__ float rv[NW];
  __shared__ int ri[NW];
  __shared__ float rmn[NW];
  __shared__ unsigned sng[NW];
  __shared__ float statb[4];

  // ---- load raw row ----
  float raw[RPT];
  #pragma unroll
  for (int j = 0; j < RPT; ++j) raw[j] = scores[(size_t)b * NN + tid + NT * j];

  // ---- fused global min/max/neg + device spin-barrier ----
  {
    float mx = -INFINITY, mn = INFINITY; unsigned neg = 0u;
    #pragma unroll
    for (int j = 0; j < RPT; ++j){
      float v = raw[j];
      mx = fmaxf(mx, v);
      if (v == -INFINITY) neg = 1u; else mn = fminf(mn, v);
    }
    #pragma unroll
    for (int off = 32; off; off >>= 1){
      mx = fmaxf(mx, __shfl_xor(mx, off));
      mn = fminf(mn, __shfl_xor(mn, off));
      neg |= (unsigned)__shfl_xor((int)neg, off);
    }
    if (lane == 0){ rv[wv] = mx; rmn[wv] = mn; sng[wv] = neg; }
    __syncthreads();
    if (tid == 0){
      for (int q = 1; q < NW; ++q){
        mx = fmaxf(mx, rv[q]); mn = fminf(mn, rmn[q]); neg |= sng[q];
      }
      atomicMax(&ws[0], enc_f32(mx));
      atomicMin(&ws[5], enc_f32(mn));
      if (neg) atomicOr(&ws[1], 1u);
      __threadfence();
      atomicAdd(&ws[3], 1u);
      while (__hip_atomic_load(&ws[3], __ATOMIC_ACQUIRE, __HIP_MEMORY_SCOPE_AGENT) < (unsigned)BSZ)
        __builtin_amdgcn_s_sleep(2);
      statb[0] = dec_f32(__hip_atomic_load(&ws[0], __ATOMIC_RELAXED, __HIP_MEMORY_SCOPE_AGENT));
      statb[1] = dec_f32(__hip_atomic_load(&ws[5], __ATOMIC_RELAXED, __HIP_MEMORY_SCOPE_AGENT));
      statb[2] = __hip_atomic_load(&ws[1], __ATOMIC_RELAXED, __HIP_MEMORY_SCOPE_AGENT) ? 1.0f : 0.0f;
    }
    __syncthreads();
  }

  const float smax = statb[0];
  const float smin_raw = statb[1];
  const bool has_neg = statb[2] != 0.0f;
  const float filled = smin_raw - (smax - smin_raw);
  const float smin_eff = has_neg ? filled : smin_raw;
  const float cmax = fmaxf(fmaxf(smin_eff * smin_eff, smax * smax),
                           fmaxf((smin_eff - 15.0f) * (smin_eff - 15.0f),
                                 (smax - 15.0f) * (smax - 15.0f)));
  const float cinv = 1.0f / cmax;
  const float tauv = taup[0];
  const float invtau = 1.0f / tauv;       // exact divide, once
  const float inv_n = 1.0f / (float)NN;   // 2^-12, exact

  // ---- fixed s values into scratch (also used for top-k) ----
  #pragma unroll
  for (int j = 0; j < RPT; ++j){
    float v = raw[j]; if (v == -INFINITY) v = filled;
    scratch[tid + NT * j] = v;
  }
  __syncthreads();

  // ---- top-15 by iterative argmax (lane<8 shfl merge, no serial scan) ----
  for (int t = 0; t < KK; ++t){
    float bv = -INFINITY; int bi = NN;
    #pragma unroll
    for (int j = 0; j < RPT; ++j){
      int i = tid + NT * j;
      float v = scratch[i];
      if (v > bv){ bv = v; bi = i; }
    }
    #pragma unroll
    for (int off = 32; off; off >>= 1){
      float ov = __shfl_xor(bv, off);
      int oi = __shfl_xor(bi, off);
      if (ov > bv || (ov == bv && oi < bi)){ bv = ov; bi = oi; }
    }
    if (lane == 0){ rv[wv] = bv; ri[wv] = bi; }
    __syncthreads();
    {
      float mv = -INFINITY; int mi = NN;
      if (tid < NW){ mv = rv[tid]; mi = ri[tid]; }
      #pragma unroll
      for (int off = 4; off; off >>= 1){
        float ov = __shfl_xor(mv, off);
        int oi = __shfl_xor(mi, off);
        if (ov > mv || (ov == mv && oi < mi)){ mv = ov; mi = oi; }
      }
      if (tid == 0){
        tk[t] = mv; tki[t] = mi;
        scratch[mi] = -INFINITY;
      }
    }
    __syncthreads();
  }
  // restore the 15 extracted values so scratch holds the full filled s row
  if (tid < KK) scratch[tki[tid]] = tk[tid];
  __syncthreads();

  // ---- Gamma0 column sums (fast sigmoid: rcp + native exp; feeds colr/warm/nrm only) ----
  {
    float p[K1];
    float tkr[KK];
    #pragma unroll
    for (int c = 0; c < KK; ++c) tkr[c] = tk[c];
    #pragma unroll
    for (int c = 0; c < K1; ++c) p[c] = 0.0f;
    #pragma unroll
    for (int j = 0; j < RPT; ++j){
      float si = scratch[tid + NT * j];
      #pragma unroll
      for (int c = 0; c < KK; ++c){
        float z = fabsf(tkr[c] - si) * invtau;
        float raw1 = __builtin_amdgcn_rcpf(1.0f + __expf(z)) + SMALLC;
        p[c] += raw1;
      }
    }
    block_fold16(p, wbuf, cbuf, lane, wv, tid);
  }

  // ---- warm start x_r = <b, weight2[r,:]> ----
  float colinv_n[KK];   // (1/colsum_c) * inv_n, reused in epilogue
  {
    float p[K1];
    float tkr[KK];
    #pragma unroll
    for (int c = 0; c < KK; ++c){
      tkr[c] = tk[c];
      colinv_n[c] = (1.0f / cbuf[c]) * inv_n;   // exact divide, once per c
    }
    #pragma unroll
    for (int c = 0; c < K1; ++c) p[c] = 0.0f;
    #pragma unroll
    for (int j = 0; j < RPT; ++j){
      int i = tid + NT * j;
      float si = scratch[i];
      float bb[K1];
      float rowpart = 0.0f;
      #pragma unroll
      for (int c = 0; c < KK; ++c){
        float d = si - (float)(KK - c);
        float Cc = d * d * cinv;
        float z = fabsf(tkr[c] - si) * invtau;
        float raw1 = __builtin_amdgcn_rcpf(1.0f + __expf(z)) + SMALLC;
        float g0 = raw1 * colinv_n[c];
        rowpart += g0;
        bb[c] = Cc + EPSI * __logf(g0);
      }
      {
        float Cc = si * si * cinv;  // anchor 0 for c=15
        float g0l = fminf(fmaxf(inv_n - rowpart, SMALLC), 1.0f - SMALLC);
        bb[KK] = Cc + EPSI * __logf(g0l);
      }
      #pragma unroll
      for (int r = 0; r < 5; ++r){
        const float4* wp = (const float4*)(w2 + (size_t)r * W2STRIDE + (size_t)i * K1);
        float4 a0 = wp[0], a1 = wp[1], a2 = wp[2], a3 = wp[3];
        float acc = p[r];
        acc += bb[0] * a0.x + bb[1] * a0.y + bb[2] * a0.z + bb[3] * a0.w;
        acc += bb[4] * a1.x + bb[5] * a1.y + bb[6] * a1.z + bb[7] * a1.w;
        acc += bb[8] * a2.x + bb[9] * a2.y + bb[10] * a2.z + bb[11] * a2.w;
        acc += bb[12] * a3.x + bb[13] * a3.y + bb[14] * a3.z + bb[15] * a3.w;
        p[r] = acc;
      }
    }
    block_fold16(p, wbuf, xbuf, lane, wv, tid);
  }

  // ---- vt init: vt_c = B_c * exp(g_c/eps); vt[15] = 1 ----
  float vt[K1];
  {
    float xv[5];
    #pragma unroll
    for (int r = 0; r < 5; ++r) xv[r] = xbuf[r];
    #pragma unroll
    for (int c = 0; c < KK; ++c){
      float g = 0.0f;
      #pragma unroll
      for (int r = 0; r < 5; ++r) g += xv[r] * w1[(size_t)(NN + c) * 5 + r];
      float Bc = expf(-10.0f * cinv * (float)((KK - c) * (KK - c)));
      vt[c] = Bc * expf(g * 10.0f);
    }
    vt[KK] = 1.0f;
  }

  // ---- x per row pair + iteration-invariant power table xp[q][c] = x^c ----
  // (x2/xp define the kernel matrix -> keep exact expf path)
  f2 x2[NPAIR];
  #pragma unroll
  for (int q = 0; q < NPAIR; ++q){
    float s0 = scratch[tid + NT * (2 * q)];
    float s1 = scratch[tid + NT * (2 * q + 1)];
    x2[q].x = expf(s0 * (-20.0f * cinv));
    x2[q].y = expf(s1 * (-20.0f * cinv));
  }
  f2 xp[NPAIR][K1];
  #pragma unroll
  for (int q = 0; q < NPAIR; ++q){
    xp[q][0].x = 1.0f; xp[q][0].y = 1.0f;
    xp[q][1] = x2[q];
    #pragma unroll
    for (int c = 2; c < K1; ++c) xp[q][c] = xp[q][c - 1] * x2[q];
  }

  // ---- Sinkhorn: synchronized loop + shared-lambda vector extrapolation ----
  // Plain sweep: t_j = 1/sum_c vt_c x^c; wnew_c = nu_c*NN / sum_j t_j x^c.
  // Every 2 applied steps, an Anderson/RRE-1 jump with SHARED lambda from
  // RELATIVE residuals r1,r2 (scale-free across the 16 columns): lambda =
  // <r1,r2>/<r1,r1>; wout_c = wnew_c*(1 + r2_c*lambda/(1-lambda)). Guards:
  // 0<lambda<0.97, per-comp bracket (whole-jump veto), any-comp-moving
  // min-step (=> no jump fires on the exit iteration, so the epilogue (t2,vt)
  // pairing stays plain-consistent, matching the reference structure).
  f2 t2[NPAIR];
  const float nmul = ((lane & 15) < KK) ? 1.0f : 4081.0f;  // nu_c * NN
  float pv2 = 0.0f, pv1 = 0.0f;  // last-two APPLIED values (lanes<16)
  int pcnt = -1;                 // consecutive plain applied steps since jump
  #pragma unroll 1
  for (int it = 0; it < NITER; ++it){
    const int ph = it & 1;
    // row sums: h_j = sum_c vt[c] * x_j^c (Horner; 4 independent chains)
    #pragma unroll
    for (int q = 0; q < NPAIR; ++q){
      f2 h; h.x = vt[KK]; h.y = vt[KK];
      #pragma unroll
      for (int c = KK - 1; c >= 0; --c){
        f2 vc; vc.x = vt[c]; vc.y = vt[c];
        h = pk_fma(h, x2[q], vc);
      }
      t2[q].x = __builtin_amdgcn_rcpf(h.x);
      t2[q].y = __builtin_amdgcn_rcpf(h.y);
    }
    // col partials: p[c] = sum_j t_j * x_j^c (independent fmas via power table)
    float p[K1];
    #pragma unroll
    for (int c = 0; c < K1; ++c){
      f2 s = t2[0] * xp[0][c];
      #pragma unroll
      for (int q = 1; q < NPAIR; ++q) s = pk_fma(t2[q], xp[q][c], s);
      p[c] = s.x + s.y;
    }
    float r = wave_fold16(p, lane);
    if (lane < 16) wbufT[ph][fold_col(lane) * TS + wv] = r;
    __syncthreads();
    float md = -1.0f;
    float wout = 0.0f;
    if (lane < 16){
      const float* wp = &wbufT[ph][lane * TS];
      float4 a4 = *(const float4*)wp;
      float4 b4 = *(const float4*)(wp + 4);
      float t = ((a4.x + a4.y) + (a4.z + a4.w)) + ((b4.x + b4.y) + (b4.z + b4.w));
      float wnew = nmul * __builtin_amdgcn_rcpf(t);
      md = fabsf(wnew - pv1) - CONV_REL * pv1;
      wout = wnew;
    }
    if (pcnt >= 1){
      // relative residuals (lanes>=16 contribute zeros)
      float r1 = 0.0f, r2 = 0.0f;
      if (lane < 16){
        float winv = __builtin_amdgcn_rcpf(wout);
        r1 = (pv1 - pv2) * winv;
        r2 = (wout - pv1) * winv;
      }
      float s12 = sum16_all(r1 * r2);
      float s11 = sum16_all(r1 * r1);
      float s12b = bcast_lane0(s12);
      float s11b = bcast_lane0(s11);
      int anymove = __any((lane < 16) && (fabsf(r2) > 4.0f * CONV_REL));
      float fac = s12b * __builtin_amdgcn_rcpf(s11b - s12b);  // lambda/(1-lambda)
      float acc = wout * (1.0f + r2 * fac);
      int okbr = (lane < 16) ? (acc > 0.1f * wout && acc < 10.0f * wout) : 1;
      int allbr = __all(okbr);
      if ((s12b > 0.0f) && (s12b < 0.97f * s11b) && anymove && allbr){
        if (lane < 16) wout = acc;
        pcnt = -1;
      }
    }
    pcnt++;
    pv2 = pv1; pv1 = wout;
    // identical data in every wave -> identical decisions -> uniform exit
    int conv = __all(md <= 0.0f);
    #pragma unroll
    for (int c = 0; c < K1; ++c)
      vt[c] = __uint_as_float((unsigned)__builtin_amdgcn_readlane(
                  (int)__float_as_uint(wout), c));
    if (conv) break;
  }

  // ---- epilogue: Gamma = x^c * (inv_n*t) * vt; A = Gamma[:,:,:15]*n; norm^2 ----
  float nrm = 0.0f;
  {
    float tkr[KK];
    #pragma unroll
    for (int c = 0; c < KK; ++c) tkr[c] = tk[c];
    #pragma unroll
    for (int q = 0; q < NPAIR; ++q){
      #pragma unroll
      for (int half = 0; half < 2; ++half){
        int i = tid + NT * (2 * q + half);
        float si = scratch[i];
        float tin = (half ? t2[q].y : t2[q].x) * inv_n;
        float rowpart = 0.0f;
        float gamv[KK];
        float gaml;
        #pragma unroll
        for (int c = 0; c < KK; ++c){
          float xc = half ? xp[q][c].y : xp[q][c].x;
          float gam = (tin * xc) * vt[c];
          float z = fabsf(tkr[c] - si) * invtau;
          float raw1 = __builtin_amdgcn_rcpf(1.0f + __expf(z)) + SMALLC;
          float g0 = raw1 * colinv_n[c];
          rowpart += g0;
          float d = gam - g0;
          nrm += d * d;
          gamv[c] = gam * (float)NN;
        }
        {
          float xc = half ? xp[q][KK].y : xp[q][KK].x;
          gaml = (tin * xc) * vt[KK];
          float g0l = fminf(fmaxf(inv_n - rowpart, SMALLC), 1.0f - SMALLC);
          float d = gaml - g0l;
          nrm += d * d;
        }
        float* op = out + (size_t)(b * NN + i) * KK;
        #pragma unroll
        for (int c = 0; c < KK; ++c) op[c] = gamv[c];   // adjacent -> merged stores
      }
    }
  }
  #pragma unroll
  for (int off = 32; off; off >>= 1) nrm += __shfl_xor(nrm, off);
  if (lane == 0) rv[wv] = nrm;
  __syncthreads();
  if (tid == 0){
    float t = 0.0f;
    for (int q = 0; q < NW; ++q) t += rv[q];
    atomicAdd(reinterpret_cast<float*>(ws) + 2, t);
    __threadfence();
    unsigned prev = atomicAdd(&ws[4], 1u);
    if (prev == (unsigned)(BSZ - 1)){
      float n2 = __hip_atomic_load(reinterpret_cast<float*>(ws) + 2,
                                   __ATOMIC_RELAXED, __HIP_MEMORY_SCOPE_AGENT);
      out[OUT_A_ELEMS] = sqrtf(n2);
    }
  }
}

extern "C" void kernel_launch(void* const* d_in, const int* in_sizes, int n_in,
                              void* d_out, int out_size, void* d_ws, size_t ws_size,
                              hipStream_t stream){
  const float* scores = (const float*)d_in[0];
  const float* tau    = (const float*)d_in[1];
  const float* w1     = (const float*)d_in[2];  // (4111, 5) row-major
  const float* w2     = (const float*)d_in[3];  // (5, 65536) row-major
  float* out = (float*)d_out;
  unsigned* ws = (unsigned*)d_ws;

  // [0]=max_enc 0, [1]=neg 0, [2]=norm 0.f, [3]=arrive 0, [4]=done 0, [5]=min_enc FF
  hipMemsetAsync(ws, 0x00, 20, stream);
  hipMemsetAsync((char*)ws + 20, 0xFF, 4, stream);

  k_main<<<BSZ, NT, 0, stream>>>(scores, tau, w1, w2, out, ws);
}